// Round 1
// 101.781 us; speedup vs baseline: 1.0545x; 1.0545x over previous
//
#include <hip/hip_runtime.h>

// x_lab [16,3,512,512] fp32, patch=3, alpha from d_in[2], out [16,2,512,512] fp32
// Each thread computes a 4-wide x 4-tall output tile: vertical register
// blocking cuts the 3x row re-read (halo) to 1.5x and halves VMEM instrs.
#define NB   16
#define HH   512
#define WW   512
#define HWSZ (HH * WW)

typedef float vfloat4 __attribute__((ext_vector_type(4)));  // native vector for nontemporal builtin

// 6 consecutive floats (col-1 .. col+4) for one row of one channel.
// Aligned float4 for cols 0..3 plus two bounds-predicated scalar loads for
// the halo. rowv is wave-uniform per s; ledge/redge affect at most one lane
// per wave. OOB -> 0 (zero padding), matching F.unfold zero-pad semantics:
// padded positions DO contribute exp(-l^2/alpha) to the softmax denominator,
// which falls out naturally from L=0 and A=B=0 here.
__device__ __forceinline__ void load_row6(const float* __restrict__ p, int base,
                                          bool rowv, bool ledge, bool redge,
                                          float v[6]) {
    vfloat4 c = (vfloat4){0.f, 0.f, 0.f, 0.f};
    float lw = 0.0f, rx = 0.0f;
    if (rowv) {
        c = *(const vfloat4*)(p + base);
        if (!ledge) lw = p[base - 1];
        if (!redge) rx = p[base + 4];
    }
    v[0] = lw; v[1] = c.x; v[2] = c.y; v[3] = c.z; v[4] = c.w; v[5] = rx;
}

__global__ __launch_bounds__(256) void WeightedAverage_kernel(
    const float* __restrict__ x,
    const int*   __restrict__ alpha_p,
    float*       __restrict__ out)
{
    int g   = blockIdx.x * 256 + threadIdx.x;   // one 4x4 tile per thread
    int col = (g & 127) << 2;                   // 128 col-groups per row
    int h0  = ((g >> 7) & 127) << 2;            // 128 row-tiles (4 rows each)
    int n   = g >> 14;                          // 128*128 tiles per image
    bool ledge = (col == 0);
    bool redge = (col + 4 == WW);

    // exp(-d^2/alpha) = exp2(d^2 * m), m = -log2(e)/alpha
    float m = -1.4426950408889634f / (float)(*alpha_p);

    const float* Lp = x + (size_t)n * 3 * HWSZ;
    const float* Ap = Lp + HWSZ;
    const float* Bp = Lp + 2 * HWSZ;

    // Source rows s=0..5 are absolute rows h0-1 .. h0+4.
    float Lr[6][6];
    int  rb[6];
    bool rv[6];
#pragma unroll
    for (int s = 0; s < 6; ++s) {
        int r = h0 - 1 + s;
        rv[s] = ((unsigned)r < (unsigned)HH);
        rb[s] = r * WW + col;
        load_row6(Lp, rb[s], rv[s], ledge, redge, Lr[s]);
    }

    float den[4][4], na[4][4], nb[4][4];
#pragma unroll
    for (int i = 0; i < 4; ++i)
#pragma unroll
        for (int j = 0; j < 4; ++j) { den[i][j] = 0.f; na[i][j] = 0.f; nb[i][j] = 0.f; }

    // Stream A/B one source row at a time; each source row s feeds the
    // (up to 3) output rows whose 3-row window contains it.
#pragma unroll
    for (int s = 0; s < 6; ++s) {
        float Ar[6], Br[6];
        load_row6(Ap, rb[s], rv[s], ledge, redge, Ar);
        load_row6(Bp, rb[s], rv[s], ledge, redge, Br);
        const int ilo = (s - 2 < 0) ? 0 : s - 2;   // compile-time after unroll
        const int ihi = (s < 3) ? s : 3;
#pragma unroll
        for (int i = ilo; i <= ihi; ++i) {
            // center pixel for output row i, col j is Lr[i+1][j+1]
#pragma unroll
            for (int dx = 0; dx < 3; ++dx) {
#pragma unroll
                for (int j = 0; j < 4; ++j) {
                    float d  = Lr[s][j + dx] - Lr[i + 1][j + 1];
                    float wt = (s == i + 1 && dx == 1) ? 1.0f : exp2f(d * d * m);
                    den[i][j] += wt;
                    na[i][j]  += wt * Ar[j + dx];
                    nb[i][j]  += wt * Br[j + dx];
                }
            }
        }
    }

    float* op = out + (size_t)n * 2 * HWSZ + (size_t)h0 * WW + col;
#pragma unroll
    for (int i = 0; i < 4; ++i) {
        float r0 = __builtin_amdgcn_rcpf(den[i][0]);
        float r1 = __builtin_amdgcn_rcpf(den[i][1]);
        float r2 = __builtin_amdgcn_rcpf(den[i][2]);
        float r3 = __builtin_amdgcn_rcpf(den[i][3]);
        vfloat4 oa = (vfloat4){na[i][0]*r0, na[i][1]*r1, na[i][2]*r2, na[i][3]*r3};
        vfloat4 ob = (vfloat4){nb[i][0]*r0, nb[i][1]*r1, nb[i][2]*r2, nb[i][3]*r3};
        __builtin_nontemporal_store(oa, (vfloat4*)(op + (size_t)i * WW));          // write-once;
        __builtin_nontemporal_store(ob, (vfloat4*)(op + (size_t)i * WW + HWSZ));   // keep L2 for input halo
    }
}

extern "C" void kernel_launch(void* const* d_in, const int* in_sizes, int n_in,
                              void* d_out, int out_size, void* d_ws, size_t ws_size,
                              hipStream_t stream) {
    const float* x     = (const float*)d_in[0];
    const int*   alpha = (const int*)d_in[2];
    float*       out   = (float*)d_out;

    int threads = NB * (HH / 4) * (WW / 4);   // 262,144 threads (16 px each)
    dim3 grid(threads / 256);                 // 1024 blocks
    WeightedAverage_kernel<<<grid, 256, 0, stream>>>(x, alpha, out);
}